// Round 1
// baseline (615.659 us; speedup 1.0000x reference)
//
#include <hip/hip_runtime.h>
#include <stdint.h>
#include <math.h>

// Problem constants (fixed by setup_inputs)
#define NROWS 65536
#define CIN   1024
#define COUT  1024
#define BN_EPS 1e-5

// Workspace layout (bytes), ws_size = 1 GiB, we use ~88 MB:
static constexpr size_t OFF_PSUM = 0;                         // double[1024][1024] = 8 MB
static constexpr size_t OFF_PSQ  = 8ull  * 1024 * 1024;       // double[1024][1024] = 8 MB
static constexpr size_t OFF_MU   = 16ull * 1024 * 1024;       // float[1024]
static constexpr size_t OFF_INV  = 16ull * 1024 * 1024 + 4096;
static constexpr size_t OFF_W8   = 17ull * 1024 * 1024;       // int8[1024][1024] = 1 MB
static constexpr size_t OFF_A8   = 24ull * 1024 * 1024;       // int8[65536][1024] = 64 MB

typedef int i32x4 __attribute__((ext_vector_type(4)));

// Async 16B global->LDS. LDS dest must be wave-uniform (HW adds lane*16);
// global src is per-lane.
__device__ __forceinline__ void gload_lds16(const void* g, void* l) {
  __builtin_amdgcn_global_load_lds(
      (const __attribute__((address_space(1))) uint32_t*)g,
      (__attribute__((address_space(3))) uint32_t*)l, 16, 0, 0);
}

// ---------------------------------------------------------------------------
// K1: per-column partial sums over 64-row chunks, fp64 accumulation.
// grid 1024 (4 blocks/CU), block 256 (4 cols each via float4).
// 8 rows unrolled -> 8 outstanding 1KB wave-loads for HBM saturation.
__global__ __launch_bounds__(256) void k_stats_partial(
    const float* __restrict__ x, double* __restrict__ psum, double* __restrict__ psq) {
  int tid = threadIdx.x;
  size_t r0 = (size_t)blockIdx.x * 64;
  const float4* xp = (const float4*)x + r0 * 256 + tid;
  double s0 = 0, s1 = 0, s2 = 0, s3 = 0;
  double q0 = 0, q1 = 0, q2 = 0, q3 = 0;
  for (int r = 0; r < 64; r += 8) {
    float4 v[8];
#pragma unroll
    for (int u = 0; u < 8; ++u) v[u] = xp[(size_t)(r + u) * 256];
#pragma unroll
    for (int u = 0; u < 8; ++u) {
      double a = (double)v[u].x, b = (double)v[u].y;
      double c = (double)v[u].z, d = (double)v[u].w;
      s0 += a; q0 = fma(a, a, q0);
      s1 += b; q1 = fma(b, b, q1);
      s2 += c; q2 = fma(c, c, q2);
      s3 += d; q3 = fma(d, d, q3);
    }
  }
  size_t base = (size_t)blockIdx.x * CIN + (size_t)tid * 4;
  double2* ps = (double2*)(psum + base);
  ps[0] = make_double2(s0, s1);
  ps[1] = make_double2(s2, s3);
  double2* pq = (double2*)(psq + base);
  pq[0] = make_double2(q0, q1);
  pq[1] = make_double2(q2, q3);
}

// K2: reduce 1024 chunk-partials per column -> mu, rsqrt(var+eps).
// grid 64 blocks; block 256 = 16 cols x 16 groups of 64 chunks; LDS combine.
__global__ __launch_bounds__(256) void k_stats_final(
    const double* __restrict__ psum, const double* __restrict__ psq,
    float* __restrict__ mu, float* __restrict__ inv) {
  __shared__ double sd[16][16];
  __shared__ double sq[16][16];
  int tid = threadIdx.x;
  int cl = tid & 15;          // column within block
  int g  = tid >> 4;          // chunk group 0..15
  int col = blockIdx.x * 16 + cl;
  double s = 0, q = 0;
  for (int i = 0; i < 64; ++i) {
    size_t chunk = (size_t)(g * 64 + i);
    s += psum[chunk * CIN + col];
    q += psq [chunk * CIN + col];
  }
  sd[g][cl] = s;
  sq[g][cl] = q;
  __syncthreads();
  if (tid < 16) {
    s = 0; q = 0;
#pragma unroll
    for (int i = 0; i < 16; ++i) { s += sd[i][tid]; q += sq[i][tid]; }
    double mean = s / (double)NROWS;
    double var  = q / (double)NROWS - mean * mean;  // population var (ddof=0)
    int c = blockIdx.x * 16 + tid;
    mu[c]  = (float)mean;
    inv[c] = (float)(1.0 / sqrt(var + (double)BN_EPS));
  }
}

// K3: binarize normalized activations -> int8 {+1,-1} (0x01 / 0xFF bytes).
// grid 8192 (8 rows/block), block 256, float4 loads, u32 packed stores.
// Exact reference op order: ((x - mu) * inv) * gamma + beta, sign at h>=0.
__global__ __launch_bounds__(256) void k_binarize_x(
    const float* __restrict__ x, const float* __restrict__ mu,
    const float* __restrict__ inv, const float* __restrict__ gamma,
    const float* __restrict__ beta, uint32_t* __restrict__ A8) {
  int tid = threadIdx.x;
  float4 M  = ((const float4*)mu)[tid];
  float4 I  = ((const float4*)inv)[tid];
  float4 G  = ((const float4*)gamma)[tid];
  float4 Bt = ((const float4*)beta)[tid];
  size_t n0 = (size_t)blockIdx.x * 8;
  const float4* xp = (const float4*)x + n0 * 256 + tid;
  for (int r = 0; r < 8; ++r) {
    float4 v = xp[(size_t)r * 256];
    float h0 = ((v.x - M.x) * I.x) * G.x + Bt.x;
    float h1 = ((v.y - M.y) * I.y) * G.y + Bt.y;
    float h2 = ((v.z - M.z) * I.z) * G.z + Bt.z;
    float h3 = ((v.w - M.w) * I.w) * G.w + Bt.w;
    uint32_t p = (h0 >= 0.0f ? 0x01u : 0xFFu)
               | ((h1 >= 0.0f ? 0x01u : 0xFFu) << 8)
               | ((h2 >= 0.0f ? 0x01u : 0xFFu) << 16)
               | ((h3 >= 0.0f ? 0x01u : 0xFFu) << 24);
    A8[(n0 + r) * 256 + tid] = p;
  }
}

// K4: binarize W rows -> int8 {+1,-1}, identical packing. grid 128.
__global__ __launch_bounds__(256) void k_binarize_w(
    const float* __restrict__ W, uint32_t* __restrict__ W8) {
  int tid = threadIdx.x;
  size_t o0 = (size_t)blockIdx.x * 8;
  const float4* wp = (const float4*)W + o0 * 256 + tid;
  for (int r = 0; r < 8; ++r) {
    float4 v = wp[(size_t)r * 256];
    uint32_t p = (v.x >= 0.0f ? 0x01u : 0xFFu)
               | ((v.y >= 0.0f ? 0x01u : 0xFFu) << 8)
               | ((v.z >= 0.0f ? 0x01u : 0xFFu) << 16)
               | ((v.w >= 0.0f ? 0x01u : 0xFFu) << 24);
    W8[(o0 + r) * 256 + tid] = p;
  }
}

// ---------------------------------------------------------------------------
// K5: i8 MFMA GEMM + fused bias/scale/PReLU.
// Tile 128x128, BK=128 bytes. Block 256 = 4 waves in 2x2; wave owns 64x64
// (4x4 fragments of 16x16, mfma_i32_16x16x64_i8, i32-exact accumulation).
//
// LDS: A/B tiles 16 KB each, staged by global_load_lds dwordx4 into a LINEAR
// destination; the XOR swizzle (byte ^= (row&7)<<4 within each 128B row) is
// applied on the GLOBAL source address at stage time and again on the
// ds_read_b128 fragment address (both-sides-or-neither, rule #21). This
// spreads the 16-lane column reads over 8 bank groups (~2-way, free) instead
// of the 16-way conflict of a plain row-major [128][128] tile.
__global__ __launch_bounds__(256) void k_mmi8(
    const int8_t* __restrict__ A8, const int8_t* __restrict__ W8,
    const float* __restrict__ bias, const float* __restrict__ scale,
    const float* __restrict__ alphaPtr, float* __restrict__ out) {
  __shared__ uint8_t As[128 * 128];  // 16 KB
  __shared__ uint8_t Bs[128 * 128];  // 16 KB
  int tid  = threadIdx.x;
  int lane = tid & 63, wv = tid >> 6;
  int wr = wv >> 1, wc = wv & 1;     // wave grid 2 (rows) x 2 (cols)
  size_t n0 = (size_t)blockIdx.y * 128;
  int c0 = blockIdx.x * 128;

  i32x4 acc[4][4] = {};

  // Stage-side swizzle: LDS linear offset L = (i*256+tid)*16 maps to tile
  // byte swz(L); row(L) = i*32 + (tid>>3); within-row col = (tid&7)*16,
  // swizzled col = ((tid&7) ^ ((tid>>3)&7)) << 4  (independent of i).
  int rsub = tid >> 3;  // 0..31
  int swzc = ((tid & 7) ^ (rsub & 7)) << 4;
  const int8_t* Asrc = A8 + (n0 + (size_t)rsub) * 1024 + swzc;
  const int8_t* Bsrc = W8 + ((size_t)c0 + rsub) * 1024 + swzc;

  for (int t = 0; t < 8; ++t) {  // K = 1024 = 8 steps of 128 bytes
#pragma unroll
    for (int i = 0; i < 4; ++i) {
      gload_lds16(Asrc + (size_t)i * 32 * 1024 + t * 128, &As[i * 4096 + wv * 1024]);
      gload_lds16(Bsrc + (size_t)i * 32 * 1024 + t * 128, &Bs[i * 4096 + wv * 1024]);
    }
    __syncthreads();  // compiler emits vmcnt(0) drain before the barrier

#pragma unroll
    for (int kk = 0; kk < 2; ++kk) {
      i32x4 af[4], bf[4];
#pragma unroll
      for (int m = 0; m < 4; ++m) {
        int row = wr * 64 + m * 16 + (lane & 15);            // row&7 == lane&7
        int col = (kk * 64 + ((lane >> 4) << 4)) ^ ((lane & 7) << 4);
        af[m] = *(const i32x4*)&As[row * 128 + col];
      }
#pragma unroll
      for (int n = 0; n < 4; ++n) {
        int row = wc * 64 + n * 16 + (lane & 15);
        int col = (kk * 64 + ((lane >> 4) << 4)) ^ ((lane & 7) << 4);
        bf[n] = *(const i32x4*)&Bs[row * 128 + col];
      }
#pragma unroll
      for (int m = 0; m < 4; ++m)
#pragma unroll
        for (int n = 0; n < 4; ++n)
          acc[m][n] = __builtin_amdgcn_mfma_i32_16x16x64_i8(af[m], bf[n], acc[m][n], 0, 0, 0);
    }
    __syncthreads();
  }

  // Epilogue. C/D layout (16x16, dtype-independent): col = lane&15,
  // row = (lane>>4)*4 + reg. dot is an exact int (|dot|<=1024) -> fp32 exact;
  // op order matches reference: y = (dot + b) * scale; PReLU.
  float alpha = alphaPtr[0];
#pragma unroll
  for (int n = 0; n < 4; ++n) {
    int col = c0 + wc * 64 + n * 16 + (lane & 15);
    float b  = bias[col];
    float sc = scale[col];
#pragma unroll
    for (int m = 0; m < 4; ++m) {
      size_t rbase = n0 + (size_t)wr * 64 + m * 16 + ((lane >> 4) << 2);
#pragma unroll
      for (int r = 0; r < 4; ++r) {
        float y = ((float)acc[m][n][r] + b) * sc;
        out[(rbase + r) * COUT + col] = y > 0.0f ? y : alpha * y;
      }
    }
  }
}

extern "C" void kernel_launch(void* const* d_in, const int* in_sizes, int n_in,
                              void* d_out, int out_size, void* d_ws, size_t ws_size,
                              hipStream_t stream) {
  const float* x     = (const float*)d_in[0];
  const float* gamma = (const float*)d_in[1];
  const float* beta  = (const float*)d_in[2];
  const float* W     = (const float*)d_in[3];
  const float* b     = (const float*)d_in[4];
  const float* scale = (const float*)d_in[5];
  const float* alpha = (const float*)d_in[6];
  float* out = (float*)d_out;

  char* ws = (char*)d_ws;
  double*   psum = (double*)(ws + OFF_PSUM);
  double*   psq  = (double*)(ws + OFF_PSQ);
  float*    mu   = (float*)(ws + OFF_MU);
  float*    inv  = (float*)(ws + OFF_INV);
  uint32_t* W8   = (uint32_t*)(ws + OFF_W8);
  uint32_t* A8   = (uint32_t*)(ws + OFF_A8);

  k_stats_partial<<<dim3(NROWS / 64), 256, 0, stream>>>(x, psum, psq);
  k_stats_final<<<dim3(CIN / 16), 256, 0, stream>>>(psum, psq, mu, inv);
  k_binarize_w<<<dim3(COUT / 8), 256, 0, stream>>>(W, W8);
  k_binarize_x<<<dim3(NROWS / 8), 256, 0, stream>>>(x, mu, inv, gamma, beta, A8);
  k_mmi8<<<dim3(COUT / 128, NROWS / 128), 256, 0, stream>>>(
      (const int8_t*)A8, (const int8_t*)W8, b, scale, alpha, out);
}

// Round 2
// 600.769 us; speedup vs baseline: 1.0248x; 1.0248x over previous
//
#include <hip/hip_runtime.h>
#include <stdint.h>
#include <math.h>

// Problem constants (fixed by setup_inputs)
#define NROWS 65536
#define CIN   1024
#define COUT  1024
#define BN_EPS 1e-5

// Workspace layout (bytes), ws_size = 1 GiB, we use ~88 MB:
static constexpr size_t OFF_PSUM = 0;                         // double[1024][1024] = 8 MB
static constexpr size_t OFF_PSQ  = 8ull  * 1024 * 1024;       // double[1024][1024] = 8 MB
static constexpr size_t OFF_MU   = 16ull * 1024 * 1024;       // float[1024]
static constexpr size_t OFF_INV  = 16ull * 1024 * 1024 + 4096;
static constexpr size_t OFF_W8   = 17ull * 1024 * 1024;       // int8[1024][1024] = 1 MB
static constexpr size_t OFF_A8   = 24ull * 1024 * 1024;       // int8[65536][1024] = 64 MB

typedef int i32x4 __attribute__((ext_vector_type(4)));

// Async 16B global->LDS. LDS dest must be wave-uniform (HW adds lane*16);
// global src is per-lane.
__device__ __forceinline__ void gload_lds16(const void* g, void* l) {
  __builtin_amdgcn_global_load_lds(
      (const __attribute__((address_space(1))) uint32_t*)g,
      (__attribute__((address_space(3))) uint32_t*)l, 16, 0, 0);
}

// ---------------------------------------------------------------------------
// K1: per-column partial sums over 64-row chunks, fp64 accumulation.
// grid 1024 (4 blocks/CU), block 256 (4 cols each via float4).
// 8 rows unrolled -> 8 outstanding 1KB wave-loads for HBM saturation.
__global__ __launch_bounds__(256) void k_stats_partial(
    const float* __restrict__ x, double* __restrict__ psum, double* __restrict__ psq) {
  int tid = threadIdx.x;
  size_t r0 = (size_t)blockIdx.x * 64;
  const float4* xp = (const float4*)x + r0 * 256 + tid;
  double s0 = 0, s1 = 0, s2 = 0, s3 = 0;
  double q0 = 0, q1 = 0, q2 = 0, q3 = 0;
  for (int r = 0; r < 64; r += 8) {
    float4 v[8];
#pragma unroll
    for (int u = 0; u < 8; ++u) v[u] = xp[(size_t)(r + u) * 256];
#pragma unroll
    for (int u = 0; u < 8; ++u) {
      double a = (double)v[u].x, b = (double)v[u].y;
      double c = (double)v[u].z, d = (double)v[u].w;
      s0 += a; q0 = fma(a, a, q0);
      s1 += b; q1 = fma(b, b, q1);
      s2 += c; q2 = fma(c, c, q2);
      s3 += d; q3 = fma(d, d, q3);
    }
  }
  size_t base = (size_t)blockIdx.x * CIN + (size_t)tid * 4;
  double2* ps = (double2*)(psum + base);
  ps[0] = make_double2(s0, s1);
  ps[1] = make_double2(s2, s3);
  double2* pq = (double2*)(psq + base);
  pq[0] = make_double2(q0, q1);
  pq[1] = make_double2(q2, q3);
}

// K2: reduce 1024 chunk-partials per column -> mu, rsqrt(var+eps).
// grid 64 blocks; block 256 = 16 cols x 16 groups of 64 chunks; LDS combine.
__global__ __launch_bounds__(256) void k_stats_final(
    const double* __restrict__ psum, const double* __restrict__ psq,
    float* __restrict__ mu, float* __restrict__ inv) {
  __shared__ double sd[16][16];
  __shared__ double sq[16][16];
  int tid = threadIdx.x;
  int cl = tid & 15;          // column within block
  int g  = tid >> 4;          // chunk group 0..15
  int col = blockIdx.x * 16 + cl;
  double s = 0, q = 0;
  for (int i = 0; i < 64; ++i) {
    size_t chunk = (size_t)(g * 64 + i);
    s += psum[chunk * CIN + col];
    q += psq [chunk * CIN + col];
  }
  sd[g][cl] = s;
  sq[g][cl] = q;
  __syncthreads();
  if (tid < 16) {
    s = 0; q = 0;
#pragma unroll
    for (int i = 0; i < 16; ++i) { s += sd[i][tid]; q += sq[i][tid]; }
    double mean = s / (double)NROWS;
    double var  = q / (double)NROWS - mean * mean;  // population var (ddof=0)
    int c = blockIdx.x * 16 + tid;
    mu[c]  = (float)mean;
    inv[c] = (float)(1.0 / sqrt(var + (double)BN_EPS));
  }
}

// K3: binarize normalized activations -> int8 {+1,-1} (0x01 / 0xFF bytes).
// grid 8192 (8 rows/block), block 256, float4 loads, u32 packed stores.
// Exact reference op order: ((x - mu) * inv) * gamma + beta, sign at h>=0.
__global__ __launch_bounds__(256) void k_binarize_x(
    const float* __restrict__ x, const float* __restrict__ mu,
    const float* __restrict__ inv, const float* __restrict__ gamma,
    const float* __restrict__ beta, uint32_t* __restrict__ A8) {
  int tid = threadIdx.x;
  float4 M  = ((const float4*)mu)[tid];
  float4 I  = ((const float4*)inv)[tid];
  float4 G  = ((const float4*)gamma)[tid];
  float4 Bt = ((const float4*)beta)[tid];
  size_t n0 = (size_t)blockIdx.x * 8;
  const float4* xp = (const float4*)x + n0 * 256 + tid;
  for (int r = 0; r < 8; ++r) {
    float4 v = xp[(size_t)r * 256];
    float h0 = ((v.x - M.x) * I.x) * G.x + Bt.x;
    float h1 = ((v.y - M.y) * I.y) * G.y + Bt.y;
    float h2 = ((v.z - M.z) * I.z) * G.z + Bt.z;
    float h3 = ((v.w - M.w) * I.w) * G.w + Bt.w;
    uint32_t p = (h0 >= 0.0f ? 0x01u : 0xFFu)
               | ((h1 >= 0.0f ? 0x01u : 0xFFu) << 8)
               | ((h2 >= 0.0f ? 0x01u : 0xFFu) << 16)
               | ((h3 >= 0.0f ? 0x01u : 0xFFu) << 24);
    A8[(n0 + r) * 256 + tid] = p;
  }
}

// K4: binarize W rows -> int8 {+1,-1}, identical packing. grid 128.
__global__ __launch_bounds__(256) void k_binarize_w(
    const float* __restrict__ W, uint32_t* __restrict__ W8) {
  int tid = threadIdx.x;
  size_t o0 = (size_t)blockIdx.x * 8;
  const float4* wp = (const float4*)W + o0 * 256 + tid;
  for (int r = 0; r < 8; ++r) {
    float4 v = wp[(size_t)r * 256];
    uint32_t p = (v.x >= 0.0f ? 0x01u : 0xFFu)
               | ((v.y >= 0.0f ? 0x01u : 0xFFu) << 8)
               | ((v.z >= 0.0f ? 0x01u : 0xFFu) << 16)
               | ((v.w >= 0.0f ? 0x01u : 0xFFu) << 24);
    W8[(o0 + r) * 256 + tid] = p;
  }
}

// ---------------------------------------------------------------------------
// K5: i8 MFMA GEMM + fused bias/scale/PReLU.
// Tile 128(M) x 256(N), BK=128 bytes. Block 512 = 8 waves in 2(M) x 4(N);
// each wave owns 64x64 (4x4 fragments of 16x16, mfma_i32_16x16x64_i8).
//
// Round-2 rationale: K5 was HBM-bound on A8 re-reads (BN=128 -> 8x re-read
// = 512 MB). BN=256 halves that to 256 MB; total K5 traffic ~532 MB -> ~85us
// HBM floor. Per-wave fragment math / swizzle identical to the verified
// round-1 kernel (absmax 0.0), only tile dims changed.
//
// LDS: A 16 KB + B 32 KB, single-buffered (48 KB -> LDS allows 3 blocks/CU;
// launch_bounds(512,4) caps VGPRs at 128 so 2 blocks/CU stay resident for
// implicit cross-block overlap of the vmcnt(0) barrier drain).
// Swizzle (both-sides, rule #21): within each 128B row, byte col ^= (row&7)<<4
// applied on the GLOBAL source at stage time and on the ds_read_b128 address.
__global__ __launch_bounds__(512, 4) void k_mmi8(
    const int8_t* __restrict__ A8, const int8_t* __restrict__ W8,
    const float* __restrict__ bias, const float* __restrict__ scale,
    const float* __restrict__ alphaPtr, float* __restrict__ out) {
  __shared__ uint8_t As[128 * 128];  // 16 KB
  __shared__ uint8_t Bs[256 * 128];  // 32 KB
  int tid  = threadIdx.x;
  int lane = tid & 63, wv = tid >> 6;       // 8 waves
  int wr = wv >> 2, wc = wv & 3;            // wave grid 2 (M) x 4 (N)
  size_t n0 = (size_t)blockIdx.y * 128;
  int c0 = blockIdx.x * 256;

  i32x4 acc[4][4] = {};

  // Stage-side swizzle: chunk c = i*512 + tid covers row = i*64 + (tid>>3),
  // within-row col = (tid&7)*16; swizzled col = ((tid&7) ^ ((tid>>3)&7)) << 4
  // (independent of i since 64 | i*64).
  int rsub = tid >> 3;  // 0..63
  int swzc = ((tid & 7) ^ (rsub & 7)) << 4;
  const int8_t* Asrc = A8 + (n0 + (size_t)rsub) * 1024 + swzc;
  const int8_t* Bsrc = W8 + ((size_t)c0 + rsub) * 1024 + swzc;

  for (int t = 0; t < 8; ++t) {  // K = 1024 = 8 steps of 128 bytes
    // A: 128 rows x 128 B = 2 chunks/thread; B: 256 rows x 128 B = 4.
#pragma unroll
    for (int i = 0; i < 2; ++i)
      gload_lds16(Asrc + (size_t)i * 64 * 1024 + t * 128, &As[i * 8192 + wv * 1024]);
#pragma unroll
    for (int i = 0; i < 4; ++i)
      gload_lds16(Bsrc + (size_t)i * 64 * 1024 + t * 128, &Bs[i * 8192 + wv * 1024]);
    __syncthreads();  // compiler emits vmcnt(0) drain before the barrier

#pragma unroll
    for (int kk = 0; kk < 2; ++kk) {
      int colb = (kk * 64 + ((lane >> 4) << 4)) ^ ((lane & 7) << 4);
      i32x4 af[4], bf[4];
#pragma unroll
      for (int m = 0; m < 4; ++m) {
        int row = wr * 64 + m * 16 + (lane & 15);            // row&7 == lane&7
        af[m] = *(const i32x4*)&As[row * 128 + colb];
      }
#pragma unroll
      for (int n = 0; n < 4; ++n) {
        int row = wc * 64 + n * 16 + (lane & 15);
        bf[n] = *(const i32x4*)&Bs[row * 128 + colb];
      }
#pragma unroll
      for (int m = 0; m < 4; ++m)
#pragma unroll
        for (int n = 0; n < 4; ++n)
          acc[m][n] = __builtin_amdgcn_mfma_i32_16x16x64_i8(af[m], bf[n], acc[m][n], 0, 0, 0);
    }
    __syncthreads();
  }

  // Epilogue. C/D layout (16x16, dtype-independent): col = lane&15,
  // row = (lane>>4)*4 + reg. dot is an exact int (|dot|<=1024) -> fp32 exact;
  // op order matches reference: y = (dot + b) * scale; PReLU.
  float alpha = alphaPtr[0];
#pragma unroll
  for (int n = 0; n < 4; ++n) {
    int col = c0 + wc * 64 + n * 16 + (lane & 15);
    float b  = bias[col];
    float sc = scale[col];
#pragma unroll
    for (int m = 0; m < 4; ++m) {
      size_t rbase = n0 + (size_t)wr * 64 + m * 16 + ((lane >> 4) << 2);
#pragma unroll
      for (int r = 0; r < 4; ++r) {
        float y = ((float)acc[m][n][r] + b) * sc;
        out[(rbase + r) * COUT + col] = y > 0.0f ? y : alpha * y;
      }
    }
  }
}

extern "C" void kernel_launch(void* const* d_in, const int* in_sizes, int n_in,
                              void* d_out, int out_size, void* d_ws, size_t ws_size,
                              hipStream_t stream) {
  const float* x     = (const float*)d_in[0];
  const float* gamma = (const float*)d_in[1];
  const float* beta  = (const float*)d_in[2];
  const float* W     = (const float*)d_in[3];
  const float* b     = (const float*)d_in[4];
  const float* scale = (const float*)d_in[5];
  const float* alpha = (const float*)d_in[6];
  float* out = (float*)d_out;

  char* ws = (char*)d_ws;
  double*   psum = (double*)(ws + OFF_PSUM);
  double*   psq  = (double*)(ws + OFF_PSQ);
  float*    mu   = (float*)(ws + OFF_MU);
  float*    inv  = (float*)(ws + OFF_INV);
  uint32_t* W8   = (uint32_t*)(ws + OFF_W8);
  uint32_t* A8   = (uint32_t*)(ws + OFF_A8);

  k_stats_partial<<<dim3(NROWS / 64), 256, 0, stream>>>(x, psum, psq);
  k_stats_final<<<dim3(CIN / 16), 256, 0, stream>>>(psum, psq, mu, inv);
  k_binarize_w<<<dim3(COUT / 8), 256, 0, stream>>>(W, W8);
  k_binarize_x<<<dim3(NROWS / 8), 256, 0, stream>>>(x, mu, inv, gamma, beta, A8);
  k_mmi8<<<dim3(COUT / 256, NROWS / 128), 512, 0, stream>>>(
      (const int8_t*)A8, (const int8_t*)W8, b, scale, alpha, out);
}

// Round 4
// 593.057 us; speedup vs baseline: 1.0381x; 1.0130x over previous
//
#include <hip/hip_runtime.h>
#include <stdint.h>
#include <math.h>

// Problem constants (fixed by setup_inputs)
#define NROWS 65536
#define CIN   1024
#define COUT  1024
#define BN_EPS 1e-5

// Workspace layout (bytes), ws_size = 1 GiB, we use ~88 MB:
static constexpr size_t OFF_PSUM = 0;                         // double[1024][1024] = 8 MB
static constexpr size_t OFF_PSQ  = 8ull  * 1024 * 1024;       // double[1024][1024] = 8 MB
static constexpr size_t OFF_MU   = 16ull * 1024 * 1024;       // float[1024]
static constexpr size_t OFF_INV  = 16ull * 1024 * 1024 + 4096;
static constexpr size_t OFF_W8   = 17ull * 1024 * 1024;       // int8[1024][1024] = 1 MB
static constexpr size_t OFF_A8   = 24ull * 1024 * 1024;       // int8[65536][1024] = 64 MB

typedef int i32x4 __attribute__((ext_vector_type(4)));

// Async 16B global->LDS. LDS dest must be wave-uniform (HW adds lane*16);
// global src is per-lane.
__device__ __forceinline__ void gload_lds16(const void* g, void* l) {
  __builtin_amdgcn_global_load_lds(
      (const __attribute__((address_space(1))) uint32_t*)g,
      (__attribute__((address_space(3))) uint32_t*)l, 16, 0, 0);
}

// ---------------------------------------------------------------------------
// K1: per-column partial sums over 64-row chunks, fp64 accumulation.
// grid 1024 (4 blocks/CU), block 256 (4 cols each via float4).
// 8 rows unrolled -> 8 outstanding 1KB wave-loads for HBM saturation.
__global__ __launch_bounds__(256) void k_stats_partial(
    const float* __restrict__ x, double* __restrict__ psum, double* __restrict__ psq) {
  int tid = threadIdx.x;
  size_t r0 = (size_t)blockIdx.x * 64;
  const float4* xp = (const float4*)x + r0 * 256 + tid;
  double s0 = 0, s1 = 0, s2 = 0, s3 = 0;
  double q0 = 0, q1 = 0, q2 = 0, q3 = 0;
  for (int r = 0; r < 64; r += 8) {
    float4 v[8];
#pragma unroll
    for (int u = 0; u < 8; ++u) v[u] = xp[(size_t)(r + u) * 256];
#pragma unroll
    for (int u = 0; u < 8; ++u) {
      double a = (double)v[u].x, b = (double)v[u].y;
      double c = (double)v[u].z, d = (double)v[u].w;
      s0 += a; q0 = fma(a, a, q0);
      s1 += b; q1 = fma(b, b, q1);
      s2 += c; q2 = fma(c, c, q2);
      s3 += d; q3 = fma(d, d, q3);
    }
  }
  size_t base = (size_t)blockIdx.x * CIN + (size_t)tid * 4;
  double2* ps = (double2*)(psum + base);
  ps[0] = make_double2(s0, s1);
  ps[1] = make_double2(s2, s3);
  double2* pq = (double2*)(psq + base);
  pq[0] = make_double2(q0, q1);
  pq[1] = make_double2(q2, q3);
}

// K2: reduce 1024 chunk-partials per column -> mu, rsqrt(var+eps).
// grid 64 blocks; block 256 = 16 cols x 16 groups of 64 chunks; LDS combine.
__global__ __launch_bounds__(256) void k_stats_final(
    const double* __restrict__ psum, const double* __restrict__ psq,
    float* __restrict__ mu, float* __restrict__ inv) {
  __shared__ double sd[16][16];
  __shared__ double sq[16][16];
  int tid = threadIdx.x;
  int cl = tid & 15;          // column within block
  int g  = tid >> 4;          // chunk group 0..15
  int col = blockIdx.x * 16 + cl;
  double s = 0, q = 0;
  for (int i = 0; i < 64; ++i) {
    size_t chunk = (size_t)(g * 64 + i);
    s += psum[chunk * CIN + col];
    q += psq [chunk * CIN + col];
  }
  sd[g][cl] = s;
  sq[g][cl] = q;
  __syncthreads();
  if (tid < 16) {
    s = 0; q = 0;
#pragma unroll
    for (int i = 0; i < 16; ++i) { s += sd[i][tid]; q += sq[i][tid]; }
    double mean = s / (double)NROWS;
    double var  = q / (double)NROWS - mean * mean;  // population var (ddof=0)
    int c = blockIdx.x * 16 + tid;
    mu[c]  = (float)mean;
    inv[c] = (float)(1.0 / sqrt(var + (double)BN_EPS));
  }
}

// K3 (+K4 fused): binarize x and W -> int8 {+1,-1} (0x01 / 0xFF bytes).
// Blocks >= 8192 handle W (8 rows each). x blocks run in REVERSED row order:
// K1 streamed x forward, so the tail of x (~200 MiB) is still L3-resident;
// reading backward turns that tail into L3 hits instead of the LRU
// worst-case (forward re-read of a cache-sized stream = ~0% hits).
// Exact reference op order: ((x - mu) * inv) * gamma + beta, sign at h>=0.
__global__ __launch_bounds__(256) void k_binarize(
    const float* __restrict__ x, const float* __restrict__ mu,
    const float* __restrict__ inv, const float* __restrict__ gamma,
    const float* __restrict__ beta, const float* __restrict__ W,
    uint32_t* __restrict__ A8, uint32_t* __restrict__ W8) {
  int tid = threadIdx.x;
  if (blockIdx.x >= 8192) {   // W path: 128 blocks, 8 rows each
    size_t o0 = (size_t)(blockIdx.x - 8192) * 8;
    const float4* wp = (const float4*)W + o0 * 256 + tid;
    for (int r = 0; r < 8; ++r) {
      float4 v = wp[(size_t)r * 256];
      uint32_t p = (v.x >= 0.0f ? 0x01u : 0xFFu)
                 | ((v.y >= 0.0f ? 0x01u : 0xFFu) << 8)
                 | ((v.z >= 0.0f ? 0x01u : 0xFFu) << 16)
                 | ((v.w >= 0.0f ? 0x01u : 0xFFu) << 24);
      W8[(o0 + r) * 256 + tid] = p;
    }
    return;
  }
  float4 M  = ((const float4*)mu)[tid];
  float4 I  = ((const float4*)inv)[tid];
  float4 G  = ((const float4*)gamma)[tid];
  float4 Bt = ((const float4*)beta)[tid];
  size_t n0 = (size_t)(8191 - blockIdx.x) * 8;   // reversed
  const float4* xp = (const float4*)x + n0 * 256 + tid;
  for (int r = 0; r < 8; ++r) {
    float4 v = xp[(size_t)r * 256];
    float h0 = ((v.x - M.x) * I.x) * G.x + Bt.x;
    float h1 = ((v.y - M.y) * I.y) * G.y + Bt.y;
    float h2 = ((v.z - M.z) * I.z) * G.z + Bt.z;
    float h3 = ((v.w - M.w) * I.w) * G.w + Bt.w;
    uint32_t p = (h0 >= 0.0f ? 0x01u : 0xFFu)
               | ((h1 >= 0.0f ? 0x01u : 0xFFu) << 8)
               | ((h2 >= 0.0f ? 0x01u : 0xFFu) << 16)
               | ((h3 >= 0.0f ? 0x01u : 0xFFu) << 24);
    A8[(n0 + r) * 256 + tid] = p;
  }
}

// ---------------------------------------------------------------------------
// K5: i8 MFMA GEMM + fused bias/scale/PReLU.
// Tile 128(M) x 256(N), BK=128 bytes. Block 512 = 8 waves in 2(M) x 4(N);
// each wave owns 64x64 (4x4 fragments of 16x16, mfma_i32_16x16x64_i8).
// Fragment math / swizzle byte-identical to the verified round-2 kernel.
//
// XCD remap (grid 2048, 2048%8==0 -> simple bijective form): XCD k gets the
// contiguous linear range [k*256, (k+1)*256); consecutive entries are the 4
// column-tiles of one row-block, so each A-tile (128 KB) stays L2-resident
// across its 4 uses instead of being re-fed from L3.
__global__ __launch_bounds__(512, 4) void k_mmi8(
    const int8_t* __restrict__ A8, const int8_t* __restrict__ W8,
    const float* __restrict__ bias, const float* __restrict__ scale,
    const float* __restrict__ alphaPtr, float* __restrict__ out) {
  __shared__ uint8_t As[128 * 128];  // 16 KB
  __shared__ uint8_t Bs[256 * 128];  // 32 KB
  int tid  = threadIdx.x;
  int lane = tid & 63, wv = tid >> 6;       // 8 waves
  int wr = wv >> 2, wc = wv & 3;            // wave grid 2 (M) x 4 (N)

  // HW linear wg id (bx fastest) -> XCD-contiguous remap.
  int lin = blockIdx.x + (int)blockIdx.y * 4;           // 0..2047
  int nl  = (lin & 7) * 256 + (lin >> 3);               // bijective (2048%8==0)
  int bx  = nl & 3;
  int by  = nl >> 2;
  size_t n0 = (size_t)by * 128;
  int c0 = bx * 256;

  i32x4 acc[4][4] = {};

  // Stage-side swizzle: chunk c = i*512 + tid covers row = i*64 + (tid>>3),
  // within-row col = (tid&7)*16; swizzled col = ((tid&7) ^ ((tid>>3)&7)) << 4
  // (independent of i since 64 | i*64).
  int rsub = tid >> 3;  // 0..63
  int swzc = ((tid & 7) ^ (rsub & 7)) << 4;
  const int8_t* Asrc = A8 + (n0 + (size_t)rsub) * 1024 + swzc;
  const int8_t* Bsrc = W8 + ((size_t)c0 + rsub) * 1024 + swzc;

  for (int t = 0; t < 8; ++t) {  // K = 1024 = 8 steps of 128 bytes
    // A: 128 rows x 128 B = 2 chunks/thread; B: 256 rows x 128 B = 4.
#pragma unroll
    for (int i = 0; i < 2; ++i)
      gload_lds16(Asrc + (size_t)i * 64 * 1024 + t * 128, &As[i * 8192 + wv * 1024]);
#pragma unroll
    for (int i = 0; i < 4; ++i)
      gload_lds16(Bsrc + (size_t)i * 64 * 1024 + t * 128, &Bs[i * 8192 + wv * 1024]);
    __syncthreads();  // compiler emits vmcnt(0) drain before the barrier

#pragma unroll
    for (int kk = 0; kk < 2; ++kk) {
      int colb = (kk * 64 + ((lane >> 4) << 4)) ^ ((lane & 7) << 4);
      i32x4 af[4], bf[4];
#pragma unroll
      for (int m = 0; m < 4; ++m) {
        int row = wr * 64 + m * 16 + (lane & 15);            // row&7 == lane&7
        af[m] = *(const i32x4*)&As[row * 128 + colb];
      }
#pragma unroll
      for (int n = 0; n < 4; ++n) {
        int row = wc * 64 + n * 16 + (lane & 15);
        bf[n] = *(const i32x4*)&Bs[row * 128 + colb];
      }
#pragma unroll
      for (int m = 0; m < 4; ++m)
#pragma unroll
        for (int n = 0; n < 4; ++n)
          acc[m][n] = __builtin_amdgcn_mfma_i32_16x16x64_i8(af[m], bf[n], acc[m][n], 0, 0, 0);
    }
    __syncthreads();
  }

  // Epilogue. C/D layout (16x16, dtype-independent): col = lane&15,
  // row = (lane>>4)*4 + reg. dot is an exact int (|dot|<=1024) -> fp32 exact;
  // op order matches reference: y = (dot + b) * scale; PReLU.
  // Stores run n-innermost so a row's 4 fragment stores (256 B of one cache
  // line span) are temporally adjacent for L2 write-combining.
  float alpha = alphaPtr[0];
  float bz[4], sc4[4];
#pragma unroll
  for (int n = 0; n < 4; ++n) {
    int col = c0 + wc * 64 + n * 16 + (lane & 15);
    bz[n]  = bias[col];
    sc4[n] = scale[col];
  }
#pragma unroll
  for (int m = 0; m < 4; ++m) {
    size_t rbase = n0 + (size_t)wr * 64 + m * 16 + ((lane >> 4) << 2);
#pragma unroll
    for (int r = 0; r < 4; ++r) {
      float* orow = out + (rbase + r) * COUT + c0 + wc * 64 + (lane & 15);
#pragma unroll
      for (int n = 0; n < 4; ++n) {
        float y = ((float)acc[m][n][r] + bz[n]) * sc4[n];
        orow[n * 16] = y > 0.0f ? y : alpha * y;
      }
    }
  }
}

extern "C" void kernel_launch(void* const* d_in, const int* in_sizes, int n_in,
                              void* d_out, int out_size, void* d_ws, size_t ws_size,
                              hipStream_t stream) {
  const float* x     = (const float*)d_in[0];
  const float* gamma = (const float*)d_in[1];
  const float* beta  = (const float*)d_in[2];
  const float* W     = (const float*)d_in[3];
  const float* b     = (const float*)d_in[4];
  const float* scale = (const float*)d_in[5];
  const float* alpha = (const float*)d_in[6];
  float* out = (float*)d_out;

  char* ws = (char*)d_ws;
  double*   psum = (double*)(ws + OFF_PSUM);
  double*   psq  = (double*)(ws + OFF_PSQ);
  float*    mu   = (float*)(ws + OFF_MU);
  float*    inv  = (float*)(ws + OFF_INV);
  uint32_t* W8   = (uint32_t*)(ws + OFF_W8);
  uint32_t* A8   = (uint32_t*)(ws + OFF_A8);

  k_stats_partial<<<dim3(NROWS / 64), 256, 0, stream>>>(x, psum, psq);
  k_stats_final<<<dim3(CIN / 16), 256, 0, stream>>>(psum, psq, mu, inv);
  k_binarize<<<dim3(NROWS / 8 + COUT / 8), 256, 0, stream>>>(
      x, mu, inv, gamma, beta, W, A8, W8);
  k_mmi8<<<dim3(COUT / 256, NROWS / 128), 512, 0, stream>>>(
      (const int8_t*)A8, (const int8_t*)W8, b, scale, alpha, out);
}